// Round 1
// baseline (1442.542 us; speedup 1.0000x reference)
//
#include <hip/hip_runtime.h>
#include <hip/hip_bf16.h>

// Problem constants
#define BB 2
#define SS 512
#define DD 768
#define HH 12
#define HDIM 64
#define EE 8
#define KK 2
#define FF 3072
#define NTOK (BB*SS)      // 1024
#define D3 (3*DD)         // 2304
#define NSLOT (NTOK*KK)   // 2048

// ---------------- small helpers ----------------

__device__ __forceinline__ float gelu_tanh(float x) {
    // jax.nn.gelu default (approximate=True)
    float x3 = x * x * x;
    float z = 0.7978845608028654f * (x + 0.044715f * x3);
    float e = __expf(-2.f * z);
    float th = (1.f - e) / (1.f + e);
    return 0.5f * x * (1.f + th);
}

__device__ __forceinline__ float block_sum256(float v, float* red) {
    #pragma unroll
    for (int off = 32; off; off >>= 1) v += __shfl_down(v, off);
    int lane = threadIdx.x & 63, w = threadIdx.x >> 6;
    if (lane == 0) red[w] = v;
    __syncthreads();
    float tot = red[0] + red[1] + red[2] + red[3];
    __syncthreads();
    return tot;
}

// ---------------- kernels ----------------

__global__ __launch_bounds__(256) void k_ln(const float* __restrict__ x,
                                            const float* __restrict__ w,
                                            const float* __restrict__ b,
                                            float* __restrict__ out) {
    __shared__ float red[4];
    int t = blockIdx.x;
    const float* xr = x + (size_t)t * DD;
    int i = threadIdx.x;
    float v0 = xr[i], v1 = xr[i + 256], v2 = xr[i + 512];
    float mu = block_sum256(v0 + v1 + v2, red) * (1.f / 768.f);
    float d0 = v0 - mu, d1 = v1 - mu, d2 = v2 - mu;
    float var = block_sum256(d0 * d0 + d1 * d1 + d2 * d2, red) * (1.f / 768.f);
    float rs = rsqrtf(var + 1e-5f);
    float* o = out + (size_t)t * DD;
    o[i]       = d0 * rs * w[i]       + b[i];
    o[i + 256] = d1 * rs * w[i + 256] + b[i + 256];
    o[i + 512] = d2 * rs * w[i + 512] + b[i + 512];
}

// Generic tiled fp32 GEMM: C[M,N] = A[M,K] @ B[K,N] + bias, optional residual.
// grid: (N/64, M/64), block 256. M,N multiples of 64, K multiple of 16.
template<int RES>
__global__ __launch_bounds__(256) void k_gemm(const float* __restrict__ A, int lda,
                                              const float* __restrict__ Bm, int ldb,
                                              const float* __restrict__ bias,
                                              const float* __restrict__ res,
                                              float* __restrict__ C, int ldc,
                                              int Kd) {
    __shared__ float As[16][68];
    __shared__ float Bs[16][64];
    int tid = threadIdx.x;
    int tx = tid & 15, ty = tid >> 4;
    int m0 = blockIdx.y * 64, n0 = blockIdx.x * 64;
    float acc[4][4] = {};
    for (int k0 = 0; k0 < Kd; k0 += 16) {
        #pragma unroll
        for (int i = 0; i < 4; ++i) {
            int idx = tid + i * 256;
            int mm = idx >> 4, kk = idx & 15;
            As[kk][mm] = A[(size_t)(m0 + mm) * lda + k0 + kk];
        }
        #pragma unroll
        for (int i = 0; i < 4; ++i) {
            int idx = tid + i * 256;
            int kk = idx >> 6, nn = idx & 63;
            Bs[kk][nn] = Bm[(size_t)(k0 + kk) * ldb + n0 + nn];
        }
        __syncthreads();
        #pragma unroll
        for (int kk = 0; kk < 16; ++kk) {
            float4 a4 = *reinterpret_cast<const float4*>(&As[kk][ty * 4]);
            float4 b4 = *reinterpret_cast<const float4*>(&Bs[kk][tx * 4]);
            float av[4] = {a4.x, a4.y, a4.z, a4.w};
            float bv[4] = {b4.x, b4.y, b4.z, b4.w};
            #pragma unroll
            for (int i = 0; i < 4; ++i)
                #pragma unroll
                for (int j = 0; j < 4; ++j) acc[i][j] += av[i] * bv[j];
        }
        __syncthreads();
    }
    #pragma unroll
    for (int i = 0; i < 4; ++i) {
        int row = m0 + ty * 4 + i;
        #pragma unroll
        for (int j = 0; j < 4; ++j) {
            int col = n0 + tx * 4 + j;
            float v = acc[i][j] + bias[col];
            if (RES) v += res[(size_t)row * ldc + col];
            C[(size_t)row * ldc + col] = v;
        }
    }
}

// Flash-style fp32 attention. grid (S/64, B*H), 64 threads; thread = one q row.
__global__ __launch_bounds__(64) void k_attn(const float* __restrict__ qkv,
                                             float* __restrict__ attn_o) {
    const int qt = blockIdx.x;
    const int bh = blockIdx.y;
    const int b = bh / HH, h = bh % HH;
    const int lane = threadIdx.x;
    const int r = qt * 64 + lane;
    __shared__ float Ks[32][64];
    __shared__ float Vs[32][64];
    const float* qptr = qkv + ((size_t)(b * SS + r)) * D3 + h * HDIM;
    float q[64];
    #pragma unroll
    for (int j = 0; j < 64; ++j) q[j] = qptr[j];
    float o[64];
    #pragma unroll
    for (int j = 0; j < 64; ++j) o[j] = 0.f;
    float m = -1e30f, l = 0.f;
    for (int kt = 0; kt < SS / 32; ++kt) {
        __syncthreads();
        for (int i = 0; i < 32; ++i) {
            int krow = kt * 32 + i;
            size_t base = ((size_t)(b * SS + krow)) * D3 + h * HDIM + lane;
            Ks[i][lane] = qkv[base + DD];
            Vs[i][lane] = qkv[base + 2 * DD];
        }
        __syncthreads();
        float s[32];
        float tmax = -1e30f;
        #pragma unroll
        for (int kk = 0; kk < 32; ++kk) {
            float acc = 0.f;
            const float4* k4 = reinterpret_cast<const float4*>(&Ks[kk][0]);
            #pragma unroll
            for (int j4 = 0; j4 < 16; ++j4) {
                float4 kv = k4[j4];
                acc += q[j4 * 4 + 0] * kv.x + q[j4 * 4 + 1] * kv.y +
                       q[j4 * 4 + 2] * kv.z + q[j4 * 4 + 3] * kv.w;
            }
            s[kk] = acc * 0.125f;  // 1/sqrt(64)
            tmax = fmaxf(tmax, s[kk]);
        }
        float m_new = fmaxf(m, tmax);
        float corr = __expf(m - m_new);
        l *= corr;
        #pragma unroll
        for (int j = 0; j < 64; ++j) o[j] *= corr;
        #pragma unroll
        for (int kk = 0; kk < 32; ++kk) {
            float p = __expf(s[kk] - m_new);
            l += p;
            const float4* v4 = reinterpret_cast<const float4*>(&Vs[kk][0]);
            #pragma unroll
            for (int j4 = 0; j4 < 16; ++j4) {
                float4 vv = v4[j4];
                o[j4 * 4 + 0] += p * vv.x; o[j4 * 4 + 1] += p * vv.y;
                o[j4 * 4 + 2] += p * vv.z; o[j4 * 4 + 3] += p * vv.w;
            }
        }
        m = m_new;
    }
    float inv = 1.f / l;
    float* optr = attn_o + ((size_t)(b * SS + r)) * DD + h * HDIM;
    #pragma unroll
    for (int j = 0; j < 64; ++j) optr[j] = o[j] * inv;
}

__global__ void k_zero(int* counts) {
    if (threadIdx.x < EE) counts[threadIdx.x] = 0;
}

// gating: logits = x @ gate_w [D,E], top-2, softmax over top-2; atomic slot positions
__global__ __launch_bounds__(64) void k_gate(const float* __restrict__ X,
                                             const float* __restrict__ gw,
                                             int* __restrict__ gate_e,
                                             float* __restrict__ gate_v,
                                             int* __restrict__ gate_pos,
                                             int* __restrict__ counts) {
    int t = blockIdx.x;
    int lane = threadIdx.x;
    const float* xr = X + (size_t)t * DD;
    float acc[EE] = {};
    for (int d = lane; d < DD; d += 64) {
        float xv = xr[d];
        #pragma unroll
        for (int e = 0; e < EE; ++e) acc[e] += xv * gw[d * EE + e];
    }
    #pragma unroll
    for (int e = 0; e < EE; ++e)
        #pragma unroll
        for (int off = 32; off; off >>= 1) acc[e] += __shfl_xor(acc[e], off);
    if (lane == 0) {
        float v0 = -1e30f; int i0 = 0;
        #pragma unroll
        for (int e = 0; e < EE; ++e) if (acc[e] > v0) { v0 = acc[e]; i0 = e; }
        float v1 = -1e30f; int i1 = 0;
        #pragma unroll
        for (int e = 0; e < EE; ++e) if (e != i0 && acc[e] > v1) { v1 = acc[e]; i1 = e; }
        float e1v = expf(v1 - v0);
        float den = 1.f + e1v;
        int p0 = atomicAdd(&counts[i0], 1);
        int p1 = atomicAdd(&counts[i1], 1);
        gate_e[2 * t] = i0;       gate_e[2 * t + 1] = i1;
        gate_v[2 * t] = 1.f / den; gate_v[2 * t + 1] = e1v / den;
        gate_pos[2 * t] = p0;     gate_pos[2 * t + 1] = p1;
    }
}

__global__ void k_scan(const int* __restrict__ counts, int* __restrict__ base) {
    if (threadIdx.x == 0) {
        int s = 0;
        for (int e = 0; e < EE; ++e) { base[e] = s; s += counts[e]; }
    }
}

__global__ void k_fill(const int* __restrict__ gate_e, const int* __restrict__ gate_pos,
                       const int* __restrict__ base, int* __restrict__ slot_token) {
    int i = blockIdx.x * 256 + threadIdx.x;
    if (i < NSLOT) {
        int e = gate_e[i];
        slot_token[base[e] + gate_pos[i]] = i >> 1;
    }
}

// MoE GEMM1: gathered rows of X (via slot_token) @ w1[e] + b1[e], GELU -> hbuf[slot][F]
// grid (F/64, N/64, E), 256 threads
__global__ __launch_bounds__(256) void k_moe1(const float* __restrict__ X,
                                              const int* __restrict__ slot_token,
                                              const int* __restrict__ base,
                                              const int* __restrict__ counts,
                                              const float* __restrict__ w1,
                                              const float* __restrict__ b1,
                                              float* __restrict__ hbuf) {
    int e = blockIdx.z;
    int cnt = counts[e];
    int mt = blockIdx.y;
    if (mt * 64 >= cnt) return;
    int nt = blockIdx.x;
    int bs = base[e];
    const float* Bm = w1 + (size_t)e * DD * FF;
    __shared__ float As[16][68];
    __shared__ float Bs[16][64];
    __shared__ int Ms[64];
    int tid = threadIdx.x;
    if (tid < 64) {
        int r = mt * 64 + tid;
        Ms[tid] = (r < cnt) ? slot_token[bs + r] : -1;
    }
    __syncthreads();
    int tx = tid & 15, ty = tid >> 4;
    int n0 = nt * 64;
    float acc[4][4] = {};
    for (int k0 = 0; k0 < DD; k0 += 16) {
        #pragma unroll
        for (int i = 0; i < 4; ++i) {
            int idx = tid + i * 256;
            int mm = idx >> 4, kk = idx & 15;
            int tok = Ms[mm];
            As[kk][mm] = (tok >= 0) ? X[(size_t)tok * DD + k0 + kk] : 0.f;
        }
        #pragma unroll
        for (int i = 0; i < 4; ++i) {
            int idx = tid + i * 256;
            int kk = idx >> 6, nn = idx & 63;
            Bs[kk][nn] = Bm[(size_t)(k0 + kk) * FF + n0 + nn];
        }
        __syncthreads();
        #pragma unroll
        for (int kk = 0; kk < 16; ++kk) {
            float4 a4 = *reinterpret_cast<const float4*>(&As[kk][ty * 4]);
            float4 b4 = *reinterpret_cast<const float4*>(&Bs[kk][tx * 4]);
            float av[4] = {a4.x, a4.y, a4.z, a4.w};
            float bv[4] = {b4.x, b4.y, b4.z, b4.w};
            #pragma unroll
            for (int i = 0; i < 4; ++i)
                #pragma unroll
                for (int j = 0; j < 4; ++j) acc[i][j] += av[i] * bv[j];
        }
        __syncthreads();
    }
    #pragma unroll
    for (int i = 0; i < 4; ++i) {
        int row = mt * 64 + ty * 4 + i;
        if (row < cnt) {
            #pragma unroll
            for (int j = 0; j < 4; ++j) {
                int col = n0 + tx * 4 + j;
                float v = acc[i][j] + b1[e * FF + col];
                hbuf[(size_t)(bs + row) * FF + col] = gelu_tanh(v);
            }
        }
    }
}

// MoE GEMM2: hbuf rows (contiguous per expert) @ w2[e] + b2[e] -> slot_out[slot][D]
// grid (D/64, N/64, E), 256 threads
__global__ __launch_bounds__(256) void k_moe2(const float* __restrict__ hbuf,
                                              const int* __restrict__ base,
                                              const int* __restrict__ counts,
                                              const float* __restrict__ w2,
                                              const float* __restrict__ b2,
                                              float* __restrict__ slot_out) {
    int e = blockIdx.z;
    int cnt = counts[e];
    int mt = blockIdx.y;
    if (mt * 64 >= cnt) return;
    int nt = blockIdx.x;
    int bs = base[e];
    const float* Bm = w2 + (size_t)e * FF * DD;
    __shared__ float As[16][68];
    __shared__ float Bs[16][64];
    int tid = threadIdx.x;
    int tx = tid & 15, ty = tid >> 4;
    int n0 = nt * 64;
    float acc[4][4] = {};
    for (int k0 = 0; k0 < FF; k0 += 16) {
        #pragma unroll
        for (int i = 0; i < 4; ++i) {
            int idx = tid + i * 256;
            int mm = idx >> 4, kk = idx & 15;
            int row = mt * 64 + mm;
            As[kk][mm] = (row < cnt) ? hbuf[(size_t)(bs + row) * FF + k0 + kk] : 0.f;
        }
        #pragma unroll
        for (int i = 0; i < 4; ++i) {
            int idx = tid + i * 256;
            int kk = idx >> 6, nn = idx & 63;
            Bs[kk][nn] = Bm[(size_t)(k0 + kk) * DD + n0 + nn];
        }
        __syncthreads();
        #pragma unroll
        for (int kk = 0; kk < 16; ++kk) {
            float4 a4 = *reinterpret_cast<const float4*>(&As[kk][ty * 4]);
            float4 b4 = *reinterpret_cast<const float4*>(&Bs[kk][tx * 4]);
            float av[4] = {a4.x, a4.y, a4.z, a4.w};
            float bv[4] = {b4.x, b4.y, b4.z, b4.w};
            #pragma unroll
            for (int i = 0; i < 4; ++i)
                #pragma unroll
                for (int j = 0; j < 4; ++j) acc[i][j] += av[i] * bv[j];
        }
        __syncthreads();
    }
    #pragma unroll
    for (int i = 0; i < 4; ++i) {
        int row = mt * 64 + ty * 4 + i;
        if (row < cnt) {
            #pragma unroll
            for (int j = 0; j < 4; ++j) {
                int col = n0 + tx * 4 + j;
                slot_out[(size_t)(bs + row) * DD + col] = acc[i][j] + b2[e * DD + col];
            }
        }
    }
}

// out = x_resid + g0*slot_out[slot0] + g1*slot_out[slot1]
__global__ __launch_bounds__(192) void k_combine(const float* __restrict__ xr,
                                                 const float* __restrict__ slot_out,
                                                 const int* __restrict__ gate_e,
                                                 const float* __restrict__ gate_v,
                                                 const int* __restrict__ gate_pos,
                                                 const int* __restrict__ base,
                                                 float* __restrict__ out) {
    int t = blockIdx.x;
    int e0 = gate_e[2 * t], e1 = gate_e[2 * t + 1];
    float g0 = gate_v[2 * t], g1 = gate_v[2 * t + 1];
    int s0 = base[e0] + gate_pos[2 * t];
    int s1 = base[e1] + gate_pos[2 * t + 1];
    int c = threadIdx.x * 4;
    float4 xv = *reinterpret_cast<const float4*>(xr + (size_t)t * DD + c);
    float4 a  = *reinterpret_cast<const float4*>(slot_out + (size_t)s0 * DD + c);
    float4 bq = *reinterpret_cast<const float4*>(slot_out + (size_t)s1 * DD + c);
    float4 r;
    r.x = xv.x + g0 * a.x + g1 * bq.x;
    r.y = xv.y + g0 * a.y + g1 * bq.y;
    r.z = xv.z + g0 * a.z + g1 * bq.z;
    r.w = xv.w + g0 * a.w + g1 * bq.w;
    *reinterpret_cast<float4*>(out + (size_t)t * DD + c) = r;
}

// ---------------- launch ----------------

extern "C" void kernel_launch(void* const* d_in, const int* in_sizes, int n_in,
                              void* d_out, int out_size, void* d_ws, size_t ws_size,
                              hipStream_t stream) {
    const float* x      = (const float*)d_in[0];
    const float* ln1_w  = (const float*)d_in[1];
    const float* ln1_b  = (const float*)d_in[2];
    const float* ln2_w  = (const float*)d_in[3];
    const float* ln2_b  = (const float*)d_in[4];
    const float* w_qkv  = (const float*)d_in[5];
    const float* b_qkv  = (const float*)d_in[6];
    const float* w_out  = (const float*)d_in[7];
    const float* b_out  = (const float*)d_in[8];
    const float* gate_w = (const float*)d_in[9];
    const float* w1     = (const float*)d_in[10];
    const float* b1     = (const float*)d_in[11];
    const float* w2     = (const float*)d_in[12];
    const float* b2     = (const float*)d_in[13];
    float* out = (float*)d_out;

    char* p = (char*)d_ws;
    auto alloc = [&](size_t bytes) -> void* {
        void* r = (void*)p;
        p += (bytes + 255) & ~(size_t)255;
        return r;
    };
    float* ln1      = (float*)alloc((size_t)NTOK * DD * 4);
    float* qkvb     = (float*)alloc((size_t)NTOK * D3 * 4);
    float* attn_o   = (float*)alloc((size_t)NTOK * DD * 4);
    float* x_resid  = (float*)alloc((size_t)NTOK * DD * 4);
    float* moe_in   = (float*)alloc((size_t)NTOK * DD * 4);
    float* hbuf     = (float*)alloc((size_t)NSLOT * FF * 4);
    float* slot_out = (float*)alloc((size_t)NSLOT * DD * 4);
    int*   gate_e   = (int*)alloc(NSLOT * 4);
    float* gate_v   = (float*)alloc(NSLOT * 4);
    int*   gate_pos = (int*)alloc(NSLOT * 4);
    int*   counts   = (int*)alloc(EE * 4);
    int*   base     = (int*)alloc(EE * 4);
    int*   slot_tok = (int*)alloc(NSLOT * 4);

    k_zero<<<1, 32, 0, stream>>>(counts);
    k_ln<<<NTOK, 256, 0, stream>>>(x, ln1_w, ln1_b, ln1);
    k_gemm<0><<<dim3(D3 / 64, NTOK / 64), 256, 0, stream>>>(
        ln1, DD, w_qkv, D3, b_qkv, nullptr, qkvb, D3, DD);
    k_attn<<<dim3(SS / 64, BB * HH), 64, 0, stream>>>(qkvb, attn_o);
    k_gemm<1><<<dim3(DD / 64, NTOK / 64), 256, 0, stream>>>(
        attn_o, DD, w_out, DD, b_out, x, x_resid, DD, DD);
    k_ln<<<NTOK, 256, 0, stream>>>(x_resid, ln2_w, ln2_b, moe_in);
    k_gate<<<NTOK, 64, 0, stream>>>(moe_in, gate_w, gate_e, gate_v, gate_pos, counts);
    k_scan<<<1, 1, 0, stream>>>(counts, base);
    k_fill<<<(NSLOT + 255) / 256, 256, 0, stream>>>(gate_e, gate_pos, base, slot_tok);
    k_moe1<<<dim3(FF / 64, NTOK / 64, EE), 256, 0, stream>>>(
        moe_in, slot_tok, base, counts, w1, b1, hbuf);
    k_moe2<<<dim3(DD / 64, NTOK / 64, EE), 256, 0, stream>>>(
        hbuf, base, counts, w2, b2, slot_out);
    k_combine<<<NTOK, 192, 0, stream>>>(x_resid, slot_out, gate_e, gate_v, gate_pos,
                                        base, out);
}

// Round 2
// 558.123 us; speedup vs baseline: 2.5846x; 2.5846x over previous
//
#include <hip/hip_runtime.h>
#include <hip/hip_bf16.h>

// Problem constants
#define BB 2
#define SS 512
#define DD 768
#define HH 12
#define HDIM 64
#define EE 8
#define FF 3072
#define NTOK (BB*SS)      // 1024
#define D3 (3*DD)         // 2304
#define NSLOT (NTOK*2)    // 2048

typedef unsigned short u16;
typedef unsigned int u32;
typedef __attribute__((ext_vector_type(8))) __bf16 bf16x8;
typedef __attribute__((ext_vector_type(4))) float f32x4;

// ---------------- helpers ----------------

__device__ __forceinline__ float gelu_tanh(float x) {
    // jax.nn.gelu default (approximate=True)
    float x3 = x * x * x;
    float z = 0.7978845608028654f * (x + 0.044715f * x3);
    float e = __expf(-2.f * z);
    float th = (1.f - e) / (1.f + e);
    return 0.5f * x * (1.f + th);
}

__device__ __forceinline__ u16 f2bf(float f) {
    union { float f; u32 u; } v; v.f = f;
    u32 r = v.u + 0x7FFF + ((v.u >> 16) & 1);   // RNE
    return (u16)(r >> 16);
}

__device__ __forceinline__ float block_sum256(float v, float* red) {
    #pragma unroll
    for (int off = 32; off; off >>= 1) v += __shfl_down(v, off);
    int lane = threadIdx.x & 63, w = threadIdx.x >> 6;
    if (lane == 0) red[w] = v;
    __syncthreads();
    float tot = red[0] + red[1] + red[2] + red[3];
    __syncthreads();
    return tot;
}

// ---------------- layernorm ----------------

__global__ __launch_bounds__(256) void k_ln(const float* __restrict__ x,
                                            const float* __restrict__ w,
                                            const float* __restrict__ b,
                                            float* __restrict__ out) {
    __shared__ float red[4];
    int t = blockIdx.x;
    const float* xr = x + (size_t)t * DD;
    int i = threadIdx.x;
    float v0 = xr[i], v1 = xr[i + 256], v2 = xr[i + 512];
    float mu = block_sum256(v0 + v1 + v2, red) * (1.f / 768.f);
    float d0 = v0 - mu, d1 = v1 - mu, d2 = v2 - mu;
    float var = block_sum256(d0 * d0 + d1 * d1 + d2 * d2, red) * (1.f / 768.f);
    float rs = rsqrtf(var + 1e-5f);
    float* o = out + (size_t)t * DD;
    o[i]       = d0 * rs * w[i]       + b[i];
    o[i + 256] = d1 * rs * w[i + 256] + b[i + 256];
    o[i + 512] = d2 * rs * w[i + 512] + b[i + 512];
}

// LN2: writes fp32 (for exact gating) + bf16 (for MFMA GEMM1)
__global__ __launch_bounds__(256) void k_ln_dual(const float* __restrict__ x,
                                                 const float* __restrict__ w,
                                                 const float* __restrict__ b,
                                                 float* __restrict__ out,
                                                 u16* __restrict__ outb) {
    __shared__ float red[4];
    int t = blockIdx.x;
    const float* xr = x + (size_t)t * DD;
    int i = threadIdx.x;
    float v0 = xr[i], v1 = xr[i + 256], v2 = xr[i + 512];
    float mu = block_sum256(v0 + v1 + v2, red) * (1.f / 768.f);
    float d0 = v0 - mu, d1 = v1 - mu, d2 = v2 - mu;
    float var = block_sum256(d0 * d0 + d1 * d1 + d2 * d2, red) * (1.f / 768.f);
    float rs = rsqrtf(var + 1e-5f);
    float* o = out + (size_t)t * DD;
    u16* ob = outb + (size_t)t * DD;
    float r0 = d0 * rs * w[i] + b[i];
    float r1 = d1 * rs * w[i + 256] + b[i + 256];
    float r2 = d2 * rs * w[i + 512] + b[i + 512];
    o[i] = r0; o[i + 256] = r1; o[i + 512] = r2;
    ob[i] = f2bf(r0); ob[i + 256] = f2bf(r1); ob[i + 512] = f2bf(r2);
}

// ---------------- fp32 GEMM (QKV / out-proj) ----------------

template<int RES>
__global__ __launch_bounds__(256) void k_gemm(const float* __restrict__ A, int lda,
                                              const float* __restrict__ Bm, int ldb,
                                              const float* __restrict__ bias,
                                              const float* __restrict__ res,
                                              float* __restrict__ C, int ldc,
                                              int Kd) {
    __shared__ float As[16][68];
    __shared__ float Bs[16][64];
    int tid = threadIdx.x;
    int tx = tid & 15, ty = tid >> 4;
    int m0 = blockIdx.y * 64, n0 = blockIdx.x * 64;
    float acc[4][4] = {};
    for (int k0 = 0; k0 < Kd; k0 += 16) {
        #pragma unroll
        for (int i = 0; i < 4; ++i) {
            int idx = tid + i * 256;
            int mm = idx >> 4, kk = idx & 15;
            As[kk][mm] = A[(size_t)(m0 + mm) * lda + k0 + kk];
        }
        #pragma unroll
        for (int i = 0; i < 4; ++i) {
            int idx = tid + i * 256;
            int kk = idx >> 6, nn = idx & 63;
            Bs[kk][nn] = Bm[(size_t)(k0 + kk) * ldb + n0 + nn];
        }
        __syncthreads();
        #pragma unroll
        for (int kk = 0; kk < 16; ++kk) {
            float4 a4 = *reinterpret_cast<const float4*>(&As[kk][ty * 4]);
            float4 b4 = *reinterpret_cast<const float4*>(&Bs[kk][tx * 4]);
            float av[4] = {a4.x, a4.y, a4.z, a4.w};
            float bv[4] = {b4.x, b4.y, b4.z, b4.w};
            #pragma unroll
            for (int i = 0; i < 4; ++i)
                #pragma unroll
                for (int j = 0; j < 4; ++j) acc[i][j] += av[i] * bv[j];
        }
        __syncthreads();
    }
    #pragma unroll
    for (int i = 0; i < 4; ++i) {
        int row = m0 + ty * 4 + i;
        #pragma unroll
        for (int j = 0; j < 4; ++j) {
            int col = n0 + tx * 4 + j;
            float v = acc[i][j] + bias[col];
            if (RES) v += res[(size_t)row * ldc + col];
            C[(size_t)row * ldc + col] = v;
        }
    }
}

// ---------------- attention: QK^T GEMM, softmax, PV GEMM ----------------

// S[bh][q][k] = Q[q]·K[k] * 0.125. grid (SS/64, SS/64, B*H), 256 thr
__global__ __launch_bounds__(256) void k_qk(const float* __restrict__ qkv,
                                            float* __restrict__ S) {
    int bh = blockIdx.z;
    int b = bh / HH, h = bh % HH;
    int m0 = blockIdx.y * 64, n0 = blockIdx.x * 64;
    const float* Q = qkv + (size_t)b * SS * D3 + h * HDIM;
    const float* Kp = Q + DD;
    __shared__ float As[16][68];
    __shared__ float Bs[16][68];
    int tid = threadIdx.x, tx = tid & 15, ty = tid >> 4;
    float acc[4][4] = {};
    for (int k0 = 0; k0 < HDIM; k0 += 16) {
        #pragma unroll
        for (int i = 0; i < 4; ++i) {
            int idx = tid + i * 256;
            int mm = idx >> 4, kk = idx & 15;
            As[kk][mm] = Q[(size_t)(m0 + mm) * D3 + k0 + kk];
            Bs[kk][mm] = Kp[(size_t)(n0 + mm) * D3 + k0 + kk];
        }
        __syncthreads();
        #pragma unroll
        for (int kk = 0; kk < 16; ++kk) {
            float4 a4 = *reinterpret_cast<const float4*>(&As[kk][ty * 4]);
            float4 b4 = *reinterpret_cast<const float4*>(&Bs[kk][tx * 4]);
            float av[4] = {a4.x, a4.y, a4.z, a4.w};
            float bv[4] = {b4.x, b4.y, b4.z, b4.w};
            #pragma unroll
            for (int i = 0; i < 4; ++i)
                #pragma unroll
                for (int j = 0; j < 4; ++j) acc[i][j] += av[i] * bv[j];
        }
        __syncthreads();
    }
    float* out = S + ((size_t)bh * SS + m0) * SS + n0;
    #pragma unroll
    for (int i = 0; i < 4; ++i)
        #pragma unroll
        for (int j = 0; j < 4; ++j)
            out[(size_t)(ty * 4 + i) * SS + tx * 4 + j] = acc[i][j] * 0.125f;
}

// row softmax over 512, in place. grid (B*H*SS) blocks, 64 thr
__global__ __launch_bounds__(64) void k_sm(float* __restrict__ S) {
    float* p = S + (size_t)blockIdx.x * SS;
    int lane = threadIdx.x;
    float v[8];
    float mx = -1e30f;
    #pragma unroll
    for (int j = 0; j < 8; ++j) { v[j] = p[lane + 64 * j]; mx = fmaxf(mx, v[j]); }
    #pragma unroll
    for (int off = 32; off; off >>= 1) mx = fmaxf(mx, __shfl_xor(mx, off));
    float s = 0.f;
    #pragma unroll
    for (int j = 0; j < 8; ++j) { v[j] = __expf(v[j] - mx); s += v[j]; }
    #pragma unroll
    for (int off = 32; off; off >>= 1) s += __shfl_xor(s, off);
    float inv = 1.f / s;
    #pragma unroll
    for (int j = 0; j < 8; ++j) p[lane + 64 * j] = v[j] * inv;
}

// attn_o[b,q,h*64+n] = sum_k P[q][k] V[k][n]. grid (SS/64, B*H), 256 thr
__global__ __launch_bounds__(256) void k_pv(const float* __restrict__ S,
                                            const float* __restrict__ qkv,
                                            float* __restrict__ attn_o) {
    int bh = blockIdx.y;
    int b = bh / HH, h = bh % HH;
    int m0 = blockIdx.x * 64;
    const float* P = S + (size_t)bh * SS * SS;
    const float* V = qkv + (size_t)b * SS * D3 + 2 * DD + h * HDIM;
    __shared__ float As[16][68];
    __shared__ float Bs[16][64];
    int tid = threadIdx.x, tx = tid & 15, ty = tid >> 4;
    float acc[4][4] = {};
    for (int k0 = 0; k0 < SS; k0 += 16) {
        #pragma unroll
        for (int i = 0; i < 4; ++i) {
            int idx = tid + i * 256;
            int mm = idx >> 4, kk = idx & 15;
            As[kk][mm] = P[(size_t)(m0 + mm) * SS + k0 + kk];
        }
        {
            int kk = tid >> 6, nn = tid & 63;
            #pragma unroll
            for (int i = 0; i < 4; ++i)
                Bs[kk + 4 * i][nn] = V[(size_t)(k0 + kk + 4 * i) * D3 + nn];
        }
        __syncthreads();
        #pragma unroll
        for (int kk = 0; kk < 16; ++kk) {
            float4 a4 = *reinterpret_cast<const float4*>(&As[kk][ty * 4]);
            float4 b4 = *reinterpret_cast<const float4*>(&Bs[kk][tx * 4]);
            float av[4] = {a4.x, a4.y, a4.z, a4.w};
            float bv[4] = {b4.x, b4.y, b4.z, b4.w};
            #pragma unroll
            for (int i = 0; i < 4; ++i)
                #pragma unroll
                for (int j = 0; j < 4; ++j) acc[i][j] += av[i] * bv[j];
        }
        __syncthreads();
    }
    float* O = attn_o + ((size_t)(b * SS + m0)) * DD + h * HDIM;
    #pragma unroll
    for (int i = 0; i < 4; ++i)
        #pragma unroll
        for (int j = 0; j < 4; ++j)
            O[(size_t)(ty * 4 + i) * DD + tx * 4 + j] = acc[i][j];
}

// ---------------- gating ----------------

__global__ void k_zero(int* counts) {
    if (threadIdx.x < EE) counts[threadIdx.x] = 0;
}

__global__ __launch_bounds__(64) void k_gate(const float* __restrict__ X,
                                             const float* __restrict__ gw,
                                             int* __restrict__ gate_e,
                                             float* __restrict__ gate_v,
                                             int* __restrict__ gate_pos,
                                             int* __restrict__ counts) {
    int t = blockIdx.x;
    int lane = threadIdx.x;
    const float* xr = X + (size_t)t * DD;
    float acc[EE] = {};
    for (int d = lane; d < DD; d += 64) {
        float xv = xr[d];
        #pragma unroll
        for (int e = 0; e < EE; ++e) acc[e] += xv * gw[d * EE + e];
    }
    #pragma unroll
    for (int e = 0; e < EE; ++e)
        #pragma unroll
        for (int off = 32; off; off >>= 1) acc[e] += __shfl_xor(acc[e], off);
    if (lane == 0) {
        float v0 = -1e30f; int i0 = 0;
        #pragma unroll
        for (int e = 0; e < EE; ++e) if (acc[e] > v0) { v0 = acc[e]; i0 = e; }
        float v1 = -1e30f; int i1 = 0;
        #pragma unroll
        for (int e = 0; e < EE; ++e) if (e != i0 && acc[e] > v1) { v1 = acc[e]; i1 = e; }
        float e1v = expf(v1 - v0);
        float den = 1.f + e1v;
        int p0 = atomicAdd(&counts[i0], 1);
        int p1 = atomicAdd(&counts[i1], 1);
        gate_e[2 * t] = i0;        gate_e[2 * t + 1] = i1;
        gate_v[2 * t] = 1.f / den; gate_v[2 * t + 1] = e1v / den;
        gate_pos[2 * t] = p0;      gate_pos[2 * t + 1] = p1;
    }
}

__global__ void k_scan(const int* __restrict__ counts, int* __restrict__ base) {
    if (threadIdx.x == 0) {
        int s = 0;
        for (int e = 0; e < EE; ++e) { base[e] = s; s += counts[e]; }
    }
}

__global__ void k_fill(const int* __restrict__ gate_e, const int* __restrict__ gate_pos,
                       const int* __restrict__ base, int* __restrict__ slot_token) {
    int i = blockIdx.x * 256 + threadIdx.x;
    if (i < NSLOT) {
        int e = gate_e[i];
        slot_token[base[e] + gate_pos[i]] = i >> 1;
    }
}

// ---------------- weight convert+transpose: fp32 [R][C] -> bf16 [C][R], per expert ----------------
// grid (C/32, R/32, E), 256 thr
__global__ __launch_bounds__(256) void k_cvtT(const float* __restrict__ src,
                                              u16* __restrict__ dst, int R, int C) {
    __shared__ float T[32][33];
    int e = blockIdx.z;
    const float* s = src + (size_t)e * R * C;
    u16* d = dst + (size_t)e * R * C;
    int c0 = blockIdx.x * 32, r0 = blockIdx.y * 32;
    int tx = threadIdx.x & 31, ty = threadIdx.x >> 5;  // ty in 0..7
    #pragma unroll
    for (int i = 0; i < 4; ++i)
        T[ty + 8 * i][tx] = s[(size_t)(r0 + ty + 8 * i) * C + c0 + tx];
    __syncthreads();
    #pragma unroll
    for (int i = 0; i < 4; ++i)
        d[(size_t)(c0 + ty + 8 * i) * R + r0 + tx] = f2bf(T[tx][ty + 8 * i]);
}

// ---------------- MoE MFMA GEMMs ----------------
// Block tile 128x128, 4 waves (2x2), each wave 64x64 via 4x4 frags of 16x16x32.
// LDS: As[128][32] bf16 (rows = M), Bs[128][32] bf16 (rows = N, K-contiguous).
// A frag: lane l -> row (l&15), k (l>>4)*8+j.  B frag: col (l&15), same k.
// D frag: row (l>>4)*4+r, col (l&15).   [per cdna4_isa §10 / m89-verified C/D]

// GEMM1: hbuf[slot][F] = gelu(gather(Xbf) @ W1t^T + b1), bf16 out
__global__ __launch_bounds__(256) void k_moe1_mm(const u16* __restrict__ Xbf,
                                                 const u16* __restrict__ W1t,  // [E][F][D]
                                                 const float* __restrict__ b1p,
                                                 const int* __restrict__ slot_token,
                                                 const int* __restrict__ base,
                                                 const int* __restrict__ counts,
                                                 u16* __restrict__ hbuf) {
    int e = blockIdx.z, cnt = counts[e];
    int mt = blockIdx.y;
    if (mt * 128 >= cnt) return;
    int bs = base[e];
    int n0 = blockIdx.x * 128;
    const u16* Bt = W1t + (size_t)e * DD * FF;
    __shared__ __align__(16) u16 As[128 * 32];
    __shared__ __align__(16) u16 Bs[128 * 32];
    __shared__ int Ms[128];
    int tid = threadIdx.x;
    if (tid < 128) {
        int r = mt * 128 + tid;
        Ms[tid] = slot_token[bs + ((r < cnt) ? r : 0)];
    }
    __syncthreads();
    int lane = tid & 63, wid = tid >> 6;
    int wm = wid >> 1, wn = wid & 1;
    f32x4 acc[4][4];
    #pragma unroll
    for (int i = 0; i < 4; ++i)
        #pragma unroll
        for (int j = 0; j < 4; ++j) acc[i][j] = (f32x4){0.f, 0.f, 0.f, 0.f};
    int arow = tid >> 2;            // 0..63
    int ac8 = (tid & 3) * 8;        // k offset in bf16
    for (int k0 = 0; k0 < DD; k0 += 32) {
        uint4 a0 = *(const uint4*)(Xbf + (size_t)Ms[arow] * DD + k0 + ac8);
        uint4 a1 = *(const uint4*)(Xbf + (size_t)Ms[arow + 64] * DD + k0 + ac8);
        uint4 bq0 = *(const uint4*)(Bt + (size_t)(n0 + arow) * DD + k0 + ac8);
        uint4 bq1 = *(const uint4*)(Bt + (size_t)(n0 + arow + 64) * DD + k0 + ac8);
        __syncthreads();
        *(uint4*)(As + arow * 32 + ac8) = a0;
        *(uint4*)(As + (arow + 64) * 32 + ac8) = a1;
        *(uint4*)(Bs + arow * 32 + ac8) = bq0;
        *(uint4*)(Bs + (arow + 64) * 32 + ac8) = bq1;
        __syncthreads();
        bf16x8 af[4], bf[4];
        #pragma unroll
        for (int i = 0; i < 4; ++i) {
            af[i] = *(const bf16x8*)(As + (wm * 64 + i * 16 + (lane & 15)) * 32 + (lane >> 4) * 8);
            bf[i] = *(const bf16x8*)(Bs + (wn * 64 + i * 16 + (lane & 15)) * 32 + (lane >> 4) * 8);
        }
        #pragma unroll
        for (int mi = 0; mi < 4; ++mi)
            #pragma unroll
            for (int ni = 0; ni < 4; ++ni)
                acc[mi][ni] = __builtin_amdgcn_mfma_f32_16x16x32_bf16(af[mi], bf[ni], acc[mi][ni], 0, 0, 0);
    }
    #pragma unroll
    for (int mi = 0; mi < 4; ++mi) {
        int rb = mt * 128 + wm * 64 + mi * 16 + ((lane >> 4) << 2);
        #pragma unroll
        for (int ni = 0; ni < 4; ++ni) {
            int col = n0 + wn * 64 + ni * 16 + (lane & 15);
            float bv = b1p[e * FF + col];
            #pragma unroll
            for (int r = 0; r < 4; ++r) {
                int row = rb + r;
                if (row < cnt)
                    hbuf[(size_t)(bs + row) * FF + col] = f2bf(gelu_tanh(acc[mi][ni][r] + bv));
            }
        }
    }
}

// GEMM2: slot_out[slot][D] = hbuf @ W2t^T + b2, fp32 out
__global__ __launch_bounds__(256) void k_moe2_mm(const u16* __restrict__ hbuf,
                                                 const u16* __restrict__ W2t,  // [E][D][F]
                                                 const float* __restrict__ b2p,
                                                 const int* __restrict__ base,
                                                 const int* __restrict__ counts,
                                                 float* __restrict__ slot_out) {
    int e = blockIdx.z, cnt = counts[e];
    int mt = blockIdx.y;
    if (mt * 128 >= cnt) return;
    int bs = base[e];
    int n0 = blockIdx.x * 128;
    const u16* Bt = W2t + (size_t)e * DD * FF;
    __shared__ __align__(16) u16 As[128 * 32];
    __shared__ __align__(16) u16 Bs[128 * 32];
    int tid = threadIdx.x;
    int lane = tid & 63, wid = tid >> 6;
    int wm = wid >> 1, wn = wid & 1;
    f32x4 acc[4][4];
    #pragma unroll
    for (int i = 0; i < 4; ++i)
        #pragma unroll
        for (int j = 0; j < 4; ++j) acc[i][j] = (f32x4){0.f, 0.f, 0.f, 0.f};
    int arow = tid >> 2;
    int ac8 = (tid & 3) * 8;
    int r0g = mt * 128 + arow, r1g = r0g + 64;
    int rr0 = (r0g < cnt) ? r0g : 0;
    int rr1 = (r1g < cnt) ? r1g : 0;
    for (int k0 = 0; k0 < FF; k0 += 32) {
        uint4 a0 = *(const uint4*)(hbuf + (size_t)(bs + rr0) * FF + k0 + ac8);
        uint4 a1 = *(const uint4*)(hbuf + (size_t)(bs + rr1) * FF + k0 + ac8);
        uint4 bq0 = *(const uint4*)(Bt + (size_t)(n0 + arow) * FF + k0 + ac8);
        uint4 bq1 = *(const uint4*)(Bt + (size_t)(n0 + arow + 64) * FF + k0 + ac8);
        __syncthreads();
        *(uint4*)(As + arow * 32 + ac8) = a0;
        *(uint4*)(As + (arow + 64) * 32 + ac8) = a1;
        *(uint4*)(Bs + arow * 32 + ac8) = bq0;
        *(uint4*)(Bs + (arow + 64) * 32 + ac8) = bq1;
        __syncthreads();
        bf16x8 af[4], bf[4];
        #pragma unroll
        for (int i = 0; i < 4; ++i) {
            af[i] = *(const bf16x8*)(As + (wm * 64 + i * 16 + (lane & 15)) * 32 + (lane >> 4) * 8);
            bf[i] = *(const bf16x8*)(Bs + (wn * 64 + i * 16 + (lane & 15)) * 32 + (lane >> 4) * 8);
        }
        #pragma unroll
        for (int mi = 0; mi < 4; ++mi)
            #pragma unroll
            for (int ni = 0; ni < 4; ++ni)
                acc[mi][ni] = __builtin_amdgcn_mfma_f32_16x16x32_bf16(af[mi], bf[ni], acc[mi][ni], 0, 0, 0);
    }
    #pragma unroll
    for (int mi = 0; mi < 4; ++mi) {
        int rb = mt * 128 + wm * 64 + mi * 16 + ((lane >> 4) << 2);
        #pragma unroll
        for (int ni = 0; ni < 4; ++ni) {
            int col = n0 + wn * 64 + ni * 16 + (lane & 15);
            float bv = b2p[e * DD + col];
            #pragma unroll
            for (int r = 0; r < 4; ++r) {
                int row = rb + r;
                if (row < cnt)
                    slot_out[(size_t)(bs + row) * DD + col] = acc[mi][ni][r] + bv;
            }
        }
    }
}

// out = x_resid + g0*slot_out[s0] + g1*slot_out[s1]
__global__ __launch_bounds__(192) void k_combine(const float* __restrict__ xr,
                                                 const float* __restrict__ slot_out,
                                                 const int* __restrict__ gate_e,
                                                 const float* __restrict__ gate_v,
                                                 const int* __restrict__ gate_pos,
                                                 const int* __restrict__ base,
                                                 float* __restrict__ out) {
    int t = blockIdx.x;
    int e0 = gate_e[2 * t], e1 = gate_e[2 * t + 1];
    float g0 = gate_v[2 * t], g1 = gate_v[2 * t + 1];
    int s0 = base[e0] + gate_pos[2 * t];
    int s1 = base[e1] + gate_pos[2 * t + 1];
    int c = threadIdx.x * 4;
    float4 xv = *reinterpret_cast<const float4*>(xr + (size_t)t * DD + c);
    float4 a  = *reinterpret_cast<const float4*>(slot_out + (size_t)s0 * DD + c);
    float4 bq = *reinterpret_cast<const float4*>(slot_out + (size_t)s1 * DD + c);
    float4 r;
    r.x = xv.x + g0 * a.x + g1 * bq.x;
    r.y = xv.y + g0 * a.y + g1 * bq.y;
    r.z = xv.z + g0 * a.z + g1 * bq.z;
    r.w = xv.w + g0 * a.w + g1 * bq.w;
    *reinterpret_cast<float4*>(out + (size_t)t * DD + c) = r;
}

// ---------------- launch ----------------

extern "C" void kernel_launch(void* const* d_in, const int* in_sizes, int n_in,
                              void* d_out, int out_size, void* d_ws, size_t ws_size,
                              hipStream_t stream) {
    const float* x      = (const float*)d_in[0];
    const float* ln1_w  = (const float*)d_in[1];
    const float* ln1_b  = (const float*)d_in[2];
    const float* ln2_w  = (const float*)d_in[3];
    const float* ln2_b  = (const float*)d_in[4];
    const float* w_qkv  = (const float*)d_in[5];
    const float* b_qkv  = (const float*)d_in[6];
    const float* w_out  = (const float*)d_in[7];
    const float* b_out  = (const float*)d_in[8];
    const float* gate_w = (const float*)d_in[9];
    const float* w1     = (const float*)d_in[10];
    const float* b1     = (const float*)d_in[11];
    const float* w2     = (const float*)d_in[12];
    const float* b2     = (const float*)d_in[13];
    float* out = (float*)d_out;

    char* p = (char*)d_ws;
    auto alloc = [&](size_t bytes) -> void* {
        void* r = (void*)p;
        p += (bytes + 255) & ~(size_t)255;
        return r;
    };
    float* ln1      = (float*)alloc((size_t)NTOK * DD * 4);
    float* qkvb     = (float*)alloc((size_t)NTOK * D3 * 4);
    float* attn_o   = (float*)alloc((size_t)NTOK * DD * 4);
    float* x_resid  = (float*)alloc((size_t)NTOK * DD * 4);
    float* moe_in   = (float*)alloc((size_t)NTOK * DD * 4);
    u16*   Xbf      = (u16*)alloc((size_t)NTOK * DD * 2);
    u16*   hbuf     = (u16*)alloc((size_t)NSLOT * FF * 2);
    float* slot_out = (float*)alloc((size_t)NSLOT * DD * 4);
    // big shared region: S (25.2MB) -> w1t (37.7MB) -> w2t (37.7MB), lifetimes disjoint
    void*  region   = alloc((size_t)EE * DD * FF * 2);   // 37.75 MB
    float* Smat = (float*)region;
    u16*   w1t  = (u16*)region;
    u16*   w2t  = (u16*)region;
    int*   gate_e   = (int*)alloc(NSLOT * 4);
    float* gate_v   = (float*)alloc(NSLOT * 4);
    int*   gate_pos = (int*)alloc(NSLOT * 4);
    int*   counts   = (int*)alloc(EE * 4);
    int*   base     = (int*)alloc(EE * 4);
    int*   slot_tok = (int*)alloc(NSLOT * 4);

    k_zero<<<1, 32, 0, stream>>>(counts);
    k_ln<<<NTOK, 256, 0, stream>>>(x, ln1_w, ln1_b, ln1);
    k_gemm<0><<<dim3(D3 / 64, NTOK / 64), 256, 0, stream>>>(
        ln1, DD, w_qkv, D3, b_qkv, nullptr, qkvb, D3, DD);
    // attention (3-pass, S is L3-resident)
    k_qk<<<dim3(SS / 64, SS / 64, BB * HH), 256, 0, stream>>>(qkvb, Smat);
    k_sm<<<BB * HH * SS, 64, 0, stream>>>(Smat);
    k_pv<<<dim3(SS / 64, BB * HH), 256, 0, stream>>>(Smat, qkvb, attn_o);
    k_gemm<1><<<dim3(DD / 64, NTOK / 64), 256, 0, stream>>>(
        attn_o, DD, w_out, DD, b_out, x, x_resid, DD, DD);
    k_ln_dual<<<NTOK, 256, 0, stream>>>(x_resid, ln2_w, ln2_b, moe_in, Xbf);
    k_gate<<<NTOK, 64, 0, stream>>>(moe_in, gate_w, gate_e, gate_v, gate_pos, counts);
    k_scan<<<1, 1, 0, stream>>>(counts, base);
    k_fill<<<(NSLOT + 255) / 256, 256, 0, stream>>>(gate_e, gate_pos, base, slot_tok);
    // w1 [E][D][F] -> w1t [E][F][D] bf16 (into region; S is dead now)
    k_cvtT<<<dim3(FF / 32, DD / 32, EE), 256, 0, stream>>>(w1, w1t, DD, FF);
    k_moe1_mm<<<dim3(FF / 128, NTOK / 128, EE), 256, 0, stream>>>(
        Xbf, w1t, b1, slot_tok, base, counts, hbuf);
    // w2 [E][F][D] -> w2t [E][D][F] bf16 (region reuse; w1t dead now)
    k_cvtT<<<dim3(DD / 32, FF / 32, EE), 256, 0, stream>>>(w2, w2t, FF, DD);
    k_moe2_mm<<<dim3(DD / 128, NTOK / 128, EE), 256, 0, stream>>>(
        hbuf, w2t, b2, base, counts, slot_out);
    k_combine<<<NTOK, 192, 0, stream>>>(x_resid, slot_out, gate_e, gate_v, gate_pos,
                                        base, out);
}

// Round 6
// 477.466 us; speedup vs baseline: 3.0212x; 1.1689x over previous
//
#include <hip/hip_runtime.h>
#include <hip/hip_bf16.h>

// Problem constants
#define BB 2
#define SS 512
#define DD 768
#define HH 12
#define HDIM 64
#define EE 8
#define FF 3072
#define NTOK (BB*SS)      // 1024
#define D3 (3*DD)         // 2304
#define NSLOT (NTOK*2)    // 2048
#define NBH (BB*HH)       // 24

typedef unsigned short u16;
typedef unsigned int u32;
typedef __attribute__((ext_vector_type(8))) __bf16 bf16x8;
typedef __attribute__((ext_vector_type(4))) float f32x4;

// ---------------- helpers ----------------

__device__ __forceinline__ float gelu_tanh(float x) {
    float x3 = x * x * x;
    float z = 0.7978845608028654f * (x + 0.044715f * x3);
    float e = __expf(-2.f * z);
    float th = (1.f - e) / (1.f + e);
    return 0.5f * x * (1.f + th);
}

__device__ __forceinline__ u16 f2bf(float f) {
    union { float f; u32 u; } v; v.f = f;
    u32 r = v.u + 0x7FFF + ((v.u >> 16) & 1);   // RNE
    return (u16)(r >> 16);
}

__device__ __forceinline__ float bf2f(u16 h) {
    union { u32 u; float f; } v; v.u = ((u32)h) << 16;
    return v.f;
}

__device__ __forceinline__ float block_sum256(float v, float* red) {
    #pragma unroll
    for (int off = 32; off; off >>= 1) v += __shfl_down(v, off);
    int lane = threadIdx.x & 63, w = threadIdx.x >> 6;
    if (lane == 0) red[w] = v;
    __syncthreads();
    float tot = red[0] + red[1] + red[2] + red[3];
    __syncthreads();
    return tot;
}

// ---------------- layernorm ----------------

__global__ __launch_bounds__(256) void k_ln_split(const float* __restrict__ x,
                                                  const float* __restrict__ w,
                                                  const float* __restrict__ b,
                                                  u16* __restrict__ oh,
                                                  u16* __restrict__ ol) {
    __shared__ float red[4];
    int t = blockIdx.x;
    const float* xr = x + (size_t)t * DD;
    int i = threadIdx.x;
    float v0 = xr[i], v1 = xr[i + 256], v2 = xr[i + 512];
    float mu = block_sum256(v0 + v1 + v2, red) * (1.f / 768.f);
    float d0 = v0 - mu, d1 = v1 - mu, d2 = v2 - mu;
    float var = block_sum256(d0 * d0 + d1 * d1 + d2 * d2, red) * (1.f / 768.f);
    float rs = rsqrtf(var + 1e-5f);
    u16* ph = oh + (size_t)t * DD;
    u16* pl = ol + (size_t)t * DD;
    float r0 = d0 * rs * w[i] + b[i];
    float r1 = d1 * rs * w[i + 256] + b[i + 256];
    float r2 = d2 * rs * w[i + 512] + b[i + 512];
    u16 h0 = f2bf(r0), h1 = f2bf(r1), h2 = f2bf(r2);
    ph[i] = h0; ph[i + 256] = h1; ph[i + 512] = h2;
    pl[i] = f2bf(r0 - bf2f(h0));
    pl[i + 256] = f2bf(r1 - bf2f(h1));
    pl[i + 512] = f2bf(r2 - bf2f(h2));
}

__global__ __launch_bounds__(256) void k_ln_dual(const float* __restrict__ x,
                                                 const float* __restrict__ w,
                                                 const float* __restrict__ b,
                                                 float* __restrict__ out,
                                                 u16* __restrict__ outb) {
    __shared__ float red[4];
    int t = blockIdx.x;
    const float* xr = x + (size_t)t * DD;
    int i = threadIdx.x;
    float v0 = xr[i], v1 = xr[i + 256], v2 = xr[i + 512];
    float mu = block_sum256(v0 + v1 + v2, red) * (1.f / 768.f);
    float d0 = v0 - mu, d1 = v1 - mu, d2 = v2 - mu;
    float var = block_sum256(d0 * d0 + d1 * d1 + d2 * d2, red) * (1.f / 768.f);
    float rs = rsqrtf(var + 1e-5f);
    float* o = out + (size_t)t * DD;
    u16* ob = outb + (size_t)t * DD;
    float r0 = d0 * rs * w[i] + b[i];
    float r1 = d1 * rs * w[i + 256] + b[i + 256];
    float r2 = d2 * rs * w[i + 512] + b[i + 512];
    o[i] = r0; o[i + 256] = r1; o[i + 512] = r2;
    ob[i] = f2bf(r0); ob[i + 256] = f2bf(r1); ob[i + 512] = f2bf(r2);
}

// ---------------- batched split-bf16 (3-term) MFMA GEMM ----------------
// C[z][M,N] = scale*((Ah+Al)[z][M,K] @ (Bh+Bl)^T[z][N,K]) + bias (+res)
// 128x128 tile, 4 waves (2x2), each wave 64x64 via 4x4 frags of 16x16x32.
template<int RES>
__global__ __launch_bounds__(256) void k_gemm_x3b(const u16* __restrict__ Ah,
                                                  const u16* __restrict__ Al,
                                                  int lda, size_t sA,
                                                  const u16* __restrict__ BtH,
                                                  const u16* __restrict__ BtL,
                                                  int ldb, size_t sB,
                                                  const float* __restrict__ bias,
                                                  const float* __restrict__ res,
                                                  float* __restrict__ C,
                                                  int ldc, size_t sC,
                                                  int Kd, float scale) {
    int z = blockIdx.z;
    Ah += (size_t)z * sA; Al += (size_t)z * sA;
    BtH += (size_t)z * sB; BtL += (size_t)z * sB;
    C += (size_t)z * sC;
    int m0 = blockIdx.y * 128, n0 = blockIdx.x * 128;
    __shared__ __align__(16) u16 AsH[128 * 32];
    __shared__ __align__(16) u16 AsL[128 * 32];
    __shared__ __align__(16) u16 BsH[128 * 32];
    __shared__ __align__(16) u16 BsL[128 * 32];
    int tid = threadIdx.x;
    int lane = tid & 63, wid = tid >> 6;
    int wm = wid >> 1, wn = wid & 1;
    f32x4 acc[4][4];
    #pragma unroll
    for (int i = 0; i < 4; ++i)
        #pragma unroll
        for (int j = 0; j < 4; ++j) acc[i][j] = (f32x4){0.f, 0.f, 0.f, 0.f};
    int arow = tid >> 2;            // 0..63
    int ac8 = (tid & 3) * 8;        // k offset
    for (int k0 = 0; k0 < Kd; k0 += 32) {
        uint4 a0h = *(const uint4*)(Ah + (size_t)(m0 + arow) * lda + k0 + ac8);
        uint4 a1h = *(const uint4*)(Ah + (size_t)(m0 + arow + 64) * lda + k0 + ac8);
        uint4 a0l = *(const uint4*)(Al + (size_t)(m0 + arow) * lda + k0 + ac8);
        uint4 a1l = *(const uint4*)(Al + (size_t)(m0 + arow + 64) * lda + k0 + ac8);
        uint4 b0h = *(const uint4*)(BtH + (size_t)(n0 + arow) * ldb + k0 + ac8);
        uint4 b1h = *(const uint4*)(BtH + (size_t)(n0 + arow + 64) * ldb + k0 + ac8);
        uint4 b0l = *(const uint4*)(BtL + (size_t)(n0 + arow) * ldb + k0 + ac8);
        uint4 b1l = *(const uint4*)(BtL + (size_t)(n0 + arow + 64) * ldb + k0 + ac8);
        __syncthreads();
        *(uint4*)(AsH + arow * 32 + ac8) = a0h;
        *(uint4*)(AsH + (arow + 64) * 32 + ac8) = a1h;
        *(uint4*)(AsL + arow * 32 + ac8) = a0l;
        *(uint4*)(AsL + (arow + 64) * 32 + ac8) = a1l;
        *(uint4*)(BsH + arow * 32 + ac8) = b0h;
        *(uint4*)(BsH + (arow + 64) * 32 + ac8) = b1h;
        *(uint4*)(BsL + arow * 32 + ac8) = b0l;
        *(uint4*)(BsL + (arow + 64) * 32 + ac8) = b1l;
        __syncthreads();
        bf16x8 afH[4], afL[4], bfH[4], bfL[4];
        #pragma unroll
        for (int i = 0; i < 4; ++i) {
            int ao = (wm * 64 + i * 16 + (lane & 15)) * 32 + (lane >> 4) * 8;
            int bo = (wn * 64 + i * 16 + (lane & 15)) * 32 + (lane >> 4) * 8;
            afH[i] = *(const bf16x8*)(AsH + ao);
            afL[i] = *(const bf16x8*)(AsL + ao);
            bfH[i] = *(const bf16x8*)(BsH + bo);
            bfL[i] = *(const bf16x8*)(BsL + bo);
        }
        #pragma unroll
        for (int mi = 0; mi < 4; ++mi)
            #pragma unroll
            for (int ni = 0; ni < 4; ++ni) {
                acc[mi][ni] = __builtin_amdgcn_mfma_f32_16x16x32_bf16(afL[mi], bfH[ni], acc[mi][ni], 0, 0, 0);
                acc[mi][ni] = __builtin_amdgcn_mfma_f32_16x16x32_bf16(afH[mi], bfL[ni], acc[mi][ni], 0, 0, 0);
                acc[mi][ni] = __builtin_amdgcn_mfma_f32_16x16x32_bf16(afH[mi], bfH[ni], acc[mi][ni], 0, 0, 0);
            }
    }
    #pragma unroll
    for (int mi = 0; mi < 4; ++mi) {
        int rb = m0 + wm * 64 + mi * 16 + ((lane >> 4) << 2);
        #pragma unroll
        for (int ni = 0; ni < 4; ++ni) {
            int col = n0 + wn * 64 + ni * 16 + (lane & 15);
            float bv = bias ? bias[col] : 0.f;
            #pragma unroll
            for (int r = 0; r < 4; ++r) {
                int row = rb + r;
                float v = acc[mi][ni][r] * scale + bv;
                if (RES) v += res[(size_t)row * ldc + col];
                C[(size_t)row * ldc + col] = v;
            }
        }
    }
}

// ---------------- attention (MFMA path) ----------------

// qkvb fp32 [1024][2304] -> qH/L,kH/L [bh][512][64] ; vtH/L [bh][64][512]
// grid (SS/64, NBH), 256 thr
__global__ __launch_bounds__(256) void k_attn_cvt(const float* __restrict__ qkvb,
                                                  u16* __restrict__ qH, u16* __restrict__ qL,
                                                  u16* __restrict__ kH, u16* __restrict__ kL,
                                                  u16* __restrict__ vtH, u16* __restrict__ vtL) {
    __shared__ float T[64][65];
    int bh = blockIdx.y;
    int b = bh / HH, h = bh % HH;
    int s0 = blockIdx.x * 64;
    int tid = threadIdx.x;
    #pragma unroll
    for (int i = 0; i < 16; ++i) {
        int idx = tid + i * 256;
        int sl = idx >> 6, d = idx & 63;
        size_t src = (size_t)(b * SS + s0 + sl) * D3 + h * HDIM + d;
        float qv = qkvb[src];
        float kv = qkvb[src + DD];
        float vv = qkvb[src + 2 * DD];
        size_t o = ((size_t)bh * SS + s0 + sl) * HDIM + d;
        u16 qh = f2bf(qv); qH[o] = qh; qL[o] = f2bf(qv - bf2f(qh));
        u16 kh = f2bf(kv); kH[o] = kh; kL[o] = f2bf(kv - bf2f(kh));
        T[sl][d] = vv;
    }
    __syncthreads();
    #pragma unroll
    for (int i = 0; i < 16; ++i) {
        int idx = tid + i * 256;
        int dd = idx >> 6, sl = idx & 63;
        float vv = T[sl][dd];
        u16 vh = f2bf(vv);
        size_t o = ((size_t)bh * HDIM + dd) * SS + s0 + sl;
        vtH[o] = vh; vtL[o] = f2bf(vv - bf2f(vh));
    }
}

// row softmax over 512 fp32 -> split bf16 P. grid (NBH*SS), 64 thr
__global__ __launch_bounds__(64) void k_sm_split(const float* __restrict__ S,
                                                 u16* __restrict__ PHo,
                                                 u16* __restrict__ PLo) {
    const float* p = S + (size_t)blockIdx.x * SS;
    u16* ph = PHo + (size_t)blockIdx.x * SS;
    u16* pl = PLo + (size_t)blockIdx.x * SS;
    int lane = threadIdx.x;
    float v[8];
    float mx = -1e30f;
    #pragma unroll
    for (int j = 0; j < 8; ++j) { v[j] = p[lane + 64 * j]; mx = fmaxf(mx, v[j]); }
    #pragma unroll
    for (int off = 32; off; off >>= 1) mx = fmaxf(mx, __shfl_xor(mx, off));
    float s = 0.f;
    #pragma unroll
    for (int j = 0; j < 8; ++j) { v[j] = __expf(v[j] - mx); s += v[j]; }
    #pragma unroll
    for (int off = 32; off; off >>= 1) s += __shfl_xor(s, off);
    float inv = 1.f / s;
    #pragma unroll
    for (int j = 0; j < 8; ++j) {
        float w = v[j] * inv;
        u16 hi = f2bf(w);
        ph[lane + 64 * j] = hi;
        pl[lane + 64 * j] = f2bf(w - bf2f(hi));
    }
}

// PV: attn_o[b,s,h*64+d] = P[bh] @ V[bh], split-x3. Block tile 128x64, 4 waves 2x2
// (each 64x32 = 4x2 frags). grid (SS/128, NBH), 256 thr.
__global__ __launch_bounds__(256) void k_pv_x3(const u16* __restrict__ PHp,
                                               const u16* __restrict__ PLp,
                                               const u16* __restrict__ vtH,
                                               const u16* __restrict__ vtL,
                                               u16* __restrict__ oH,
                                               u16* __restrict__ oL) {
    int bh = blockIdx.y;
    int b = bh / HH, h = bh % HH;
    int m0 = blockIdx.x * 128;
    size_t abase = (size_t)bh * SS * SS;
    size_t vbase = (size_t)bh * HDIM * SS;
    __shared__ __align__(16) u16 AsH[128 * 32];
    __shared__ __align__(16) u16 AsL[128 * 32];
    __shared__ __align__(16) u16 BsH[64 * 32];
    __shared__ __align__(16) u16 BsL[64 * 32];
    int tid = threadIdx.x;
    int lane = tid & 63, wid = tid >> 6;
    int wm = wid >> 1, wn = wid & 1;
    f32x4 acc[4][2];
    #pragma unroll
    for (int i = 0; i < 4; ++i)
        #pragma unroll
        for (int j = 0; j < 2; ++j) acc[i][j] = (f32x4){0.f, 0.f, 0.f, 0.f};
    int arow = tid >> 2;
    int ac8 = (tid & 3) * 8;
    for (int k0 = 0; k0 < SS; k0 += 32) {
        uint4 a0h = *(const uint4*)(PHp + abase + (size_t)(m0 + arow) * SS + k0 + ac8);
        uint4 a1h = *(const uint4*)(PHp + abase + (size_t)(m0 + arow + 64) * SS + k0 + ac8);
        uint4 a0l = *(const uint4*)(PLp + abase + (size_t)(m0 + arow) * SS + k0 + ac8);
        uint4 a1l = *(const uint4*)(PLp + abase + (size_t)(m0 + arow + 64) * SS + k0 + ac8);
        uint4 b0h = *(const uint4*)(vtH + vbase + (size_t)arow * SS + k0 + ac8);
        uint4 b0l = *(const uint4*)(vtL + vbase + (size_t)arow * SS + k0 + ac8);
        __syncthreads();
        *(uint4*)(AsH + arow * 32 + ac8) = a0h;
        *(uint4*)(AsH + (arow + 64) * 32 + ac8) = a1h;
        *(uint4*)(AsL + arow * 32 + ac8) = a0l;
        *(uint4*)(AsL + (arow + 64) * 32 + ac8) = a1l;
        *(uint4*)(BsH + arow * 32 + ac8) = b0h;
        *(uint4*)(BsL + arow * 32 + ac8) = b0l;
        __syncthreads();
        bf16x8 afH[4], afL[4], bfH[2], bfL[2];
        #pragma unroll
        for (int i = 0; i < 4; ++i) {
            int ao = (wm * 64 + i * 16 + (lane & 15)) * 32 + (lane >> 4) * 8;
            afH[i] = *(const bf16x8*)(AsH + ao);
            afL[i] = *(const bf16x8*)(AsL + ao);
        }
        #pragma unroll
        for (int i = 0; i < 2; ++i) {
            int bo = (wn * 32 + i * 16 + (lane & 15)) * 32 + (lane >> 4) * 8;
            bfH[i] = *(const bf16x8*)(BsH + bo);
            bfL[i] = *(const bf16x8*)(BsL + bo);
        }
        #pragma unroll
        for (int mi = 0; mi < 4; ++mi)
            #pragma unroll
            for (int ni = 0; ni < 2; ++ni) {
                acc[mi][ni] = __builtin_amdgcn_mfma_f32_16x16x32_bf16(afL[mi], bfH[ni], acc[mi][ni], 0, 0, 0);
                acc[mi][ni] = __builtin_amdgcn_mfma_f32_16x16x32_bf16(afH[mi], bfL[ni], acc[mi][ni], 0, 0, 0);
                acc[mi][ni] = __builtin_amdgcn_mfma_f32_16x16x32_bf16(afH[mi], bfH[ni], acc[mi][ni], 0, 0, 0);
            }
    }
    #pragma unroll
    for (int mi = 0; mi < 4; ++mi) {
        int rb = m0 + wm * 64 + mi * 16 + ((lane >> 4) << 2);
        #pragma unroll
        for (int ni = 0; ni < 2; ++ni) {
            int col = wn * 32 + ni * 16 + (lane & 15);
            #pragma unroll
            for (int r = 0; r < 4; ++r) {
                int row = rb + r;
                float v = acc[mi][ni][r];
                u16 hi = f2bf(v);
                size_t o = ((size_t)(b * SS + row)) * DD + h * HDIM + col;
                oH[o] = hi;
                oL[o] = f2bf(v - bf2f(hi));
            }
        }
    }
}

// ---------------- gating ----------------

__global__ void k_zero(int* counts) {
    if (threadIdx.x < EE) counts[threadIdx.x] = 0;
}

__global__ __launch_bounds__(64) void k_gate(const float* __restrict__ X,
                                             const float* __restrict__ gw,
                                             int* __restrict__ gate_e,
                                             float* __restrict__ gate_v,
                                             int* __restrict__ gate_pos,
                                             int* __restrict__ counts) {
    int t = blockIdx.x;
    int lane = threadIdx.x;
    const float* xr = X + (size_t)t * DD;
    float acc[EE] = {};
    for (int d = lane; d < DD; d += 64) {
        float xv = xr[d];
        #pragma unroll
        for (int e = 0; e < EE; ++e) acc[e] += xv * gw[d * EE + e];
    }
    #pragma unroll
    for (int e = 0; e < EE; ++e)
        #pragma unroll
        for (int off = 32; off; off >>= 1) acc[e] += __shfl_xor(acc[e], off);
    if (lane == 0) {
        float v0 = -1e30f; int i0 = 0;
        #pragma unroll
        for (int e = 0; e < EE; ++e) if (acc[e] > v0) { v0 = acc[e]; i0 = e; }
        float v1 = -1e30f; int i1 = 0;
        #pragma unroll
        for (int e = 0; e < EE; ++e) if (e != i0 && acc[e] > v1) { v1 = acc[e]; i1 = e; }
        float e1v = expf(v1 - v0);
        float den = 1.f + e1v;
        int p0 = atomicAdd(&counts[i0], 1);
        int p1 = atomicAdd(&counts[i1], 1);
        gate_e[2 * t] = i0;        gate_e[2 * t + 1] = i1;
        gate_v[2 * t] = 1.f / den; gate_v[2 * t + 1] = e1v / den;
        gate_pos[2 * t] = p0;      gate_pos[2 * t + 1] = p1;
    }
}

__global__ void k_scan(const int* __restrict__ counts, int* __restrict__ base) {
    if (threadIdx.x == 0) {
        int s = 0;
        for (int e = 0; e < EE; ++e) { base[e] = s; s += counts[e]; }
    }
}

__global__ void k_fill(const int* __restrict__ gate_e, const int* __restrict__ gate_pos,
                       const int* __restrict__ base, int* __restrict__ slot_token) {
    int i = blockIdx.x * 256 + threadIdx.x;
    if (i < NSLOT) {
        int e = gate_e[i];
        slot_token[base[e] + gate_pos[i]] = i >> 1;
    }
}

// ---------------- weight convert+transpose ----------------

__global__ __launch_bounds__(256) void k_cvtT(const float* __restrict__ src,
                                              u16* __restrict__ dst, int R, int C) {
    __shared__ float T[32][33];
    int e = blockIdx.z;
    const float* s = src + (size_t)e * R * C;
    u16* d = dst + (size_t)e * R * C;
    int c0 = blockIdx.x * 32, r0 = blockIdx.y * 32;
    int tx = threadIdx.x & 31, ty = threadIdx.x >> 5;
    #pragma unroll
    for (int i = 0; i < 4; ++i)
        T[ty + 8 * i][tx] = s[(size_t)(r0 + ty + 8 * i) * C + c0 + tx];
    __syncthreads();
    #pragma unroll
    for (int i = 0; i < 4; ++i)
        d[(size_t)(c0 + ty + 8 * i) * R + r0 + tx] = f2bf(T[tx][ty + 8 * i]);
}

__global__ __launch_bounds__(256) void k_cvtT_split(const float* __restrict__ src,
                                                    u16* __restrict__ dstH,
                                                    u16* __restrict__ dstL,
                                                    int R, int C) {
    __shared__ float T[32][33];
    const float* s = src;
    int c0 = blockIdx.x * 32, r0 = blockIdx.y * 32;
    int tx = threadIdx.x & 31, ty = threadIdx.x >> 5;
    #pragma unroll
    for (int i = 0; i < 4; ++i)
        T[ty + 8 * i][tx] = s[(size_t)(r0 + ty + 8 * i) * C + c0 + tx];
    __syncthreads();
    #pragma unroll
    for (int i = 0; i < 4; ++i) {
        float v = T[tx][ty + 8 * i];
        u16 hi = f2bf(v);
        size_t idx = (size_t)(c0 + ty + 8 * i) * R + r0 + tx;
        dstH[idx] = hi;
        dstL[idx] = f2bf(v - bf2f(hi));
    }
}

// ---------------- MoE MFMA GEMMs (plain bf16) ----------------

__global__ __launch_bounds__(256) void k_moe1_mm(const u16* __restrict__ Xbf,
                                                 const u16* __restrict__ W1t,  // [E][F][D]
                                                 const float* __restrict__ b1p,
                                                 const int* __restrict__ slot_token,
                                                 const int* __restrict__ base,
                                                 const int* __restrict__ counts,
                                                 u16* __restrict__ hbuf) {
    int e = blockIdx.z, cnt = counts[e];
    int mt = blockIdx.y;
    if (mt * 128 >= cnt) return;
    int bs = base[e];
    int n0 = blockIdx.x * 128;
    const u16* Bt = W1t + (size_t)e * DD * FF;
    __shared__ __align__(16) u16 As[128 * 32];
    __shared__ __align__(16) u16 Bs[128 * 32];
    __shared__ int Ms[128];
    int tid = threadIdx.x;
    if (tid < 128) {
        int r = mt * 128 + tid;
        Ms[tid] = slot_token[bs + ((r < cnt) ? r : 0)];
    }
    __syncthreads();
    int lane = tid & 63, wid = tid >> 6;
    int wm = wid >> 1, wn = wid & 1;
    f32x4 acc[4][4];
    #pragma unroll
    for (int i = 0; i < 4; ++i)
        #pragma unroll
        for (int j = 0; j < 4; ++j) acc[i][j] = (f32x4){0.f, 0.f, 0.f, 0.f};
    int arow = tid >> 2;
    int ac8 = (tid & 3) * 8;
    for (int k0 = 0; k0 < DD; k0 += 32) {
        uint4 a0 = *(const uint4*)(Xbf + (size_t)Ms[arow] * DD + k0 + ac8);
        uint4 a1 = *(const uint4*)(Xbf + (size_t)Ms[arow + 64] * DD + k0 + ac8);
        uint4 bq0 = *(const uint4*)(Bt + (size_t)(n0 + arow) * DD + k0 + ac8);
        uint4 bq1 = *(const uint4*)(Bt + (size_t)(n0 + arow + 64) * DD + k0 + ac8);
        __syncthreads();
        *(uint4*)(As + arow * 32 + ac8) = a0;
        *(uint4*)(As + (arow + 64) * 32 + ac8) = a1;
        *(uint4*)(Bs + arow * 32 + ac8) = bq0;
        *(uint4*)(Bs + (arow + 64) * 32 + ac8) = bq1;
        __syncthreads();
        bf16x8 af[4], bf[4];
        #pragma unroll
        for (int i = 0; i < 4; ++i) {
            af[i] = *(const bf16x8*)(As + (wm * 64 + i * 16 + (lane & 15)) * 32 + (lane >> 4) * 8);
            bf[i] = *(const bf16x8*)(Bs + (wn * 64 + i * 16 + (lane & 15)) * 32 + (lane >> 4) * 8);
        }
        #pragma unroll
        for (int mi = 0; mi < 4; ++mi)
            #pragma unroll
            for (int ni = 0; ni < 4; ++ni)
                acc[mi][ni] = __builtin_amdgcn_mfma_f32_16x16x32_bf16(af[mi], bf[ni], acc[mi][ni], 0, 0, 0);
    }
    #pragma unroll
    for (int mi = 0; mi < 4; ++mi) {
        int rb = mt * 128 + wm * 64 + mi * 16 + ((lane >> 4) << 2);
        #pragma unroll
        for (int ni = 0; ni < 4; ++ni) {
            int col = n0 + wn * 64 + ni * 16 + (lane & 15);
            float bv = b1p[e * FF + col];
            #pragma unroll
            for (int r = 0; r < 4; ++r) {
                int row = rb + r;
                if (row < cnt)
                    hbuf[(size_t)(bs + row) * FF + col] = f2bf(gelu_tanh(acc[mi][ni][r] + bv));
            }
        }
    }
}

__global__ __launch_bounds__(256) void k_moe2_mm(const u16* __restrict__ hbuf,
                                                 const u16* __restrict__ W2t,  // [E][D][F]
                                                 const float* __restrict__ b2p,
                                                 const int* __restrict__ base,
                                                 const int* __restrict__ counts,
                                                 float* __restrict__ slot_out) {
    int e = blockIdx.z, cnt = counts[e];
    int mt = blockIdx.y;
    if (mt * 128 >= cnt) return;
    int bs = base[e];
    int n0 = blockIdx.x * 128;
    const u16* Bt = W2t + (size_t)e * DD * FF;
    __shared__ __align__(16) u16 As[128 * 32];
    __shared__ __align__(16) u16 Bs[128 * 32];
    int tid = threadIdx.x;
    int lane = tid & 63, wid = tid >> 6;
    int wm = wid >> 1, wn = wid & 1;
    f32x4 acc[4][4];
    #pragma unroll
    for (int i = 0; i < 4; ++i)
        #pragma unroll
        for (int j = 0; j < 4; ++j) acc[i][j] = (f32x4){0.f, 0.f, 0.f, 0.f};
    int arow = tid >> 2;
    int ac8 = (tid & 3) * 8;
    int r0g = mt * 128 + arow, r1g = r0g + 64;
    int rr0 = (r0g < cnt) ? r0g : 0;
    int rr1 = (r1g < cnt) ? r1g : 0;
    for (int k0 = 0; k0 < FF; k0 += 32) {
        uint4 a0 = *(const uint4*)(hbuf + (size_t)(bs + rr0) * FF + k0 + ac8);
        uint4 a1 = *(const uint4*)(hbuf + (size_t)(bs + rr1) * FF + k0 + ac8);
        uint4 bq0 = *(const uint4*)(Bt + (size_t)(n0 + arow) * FF + k0 + ac8);
        uint4 bq1 = *(const uint4*)(Bt + (size_t)(n0 + arow + 64) * FF + k0 + ac8);
        __syncthreads();
        *(uint4*)(As + arow * 32 + ac8) = a0;
        *(uint4*)(As + (arow + 64) * 32 + ac8) = a1;
        *(uint4*)(Bs + arow * 32 + ac8) = bq0;
        *(uint4*)(Bs + (arow + 64) * 32 + ac8) = bq1;
        __syncthreads();
        bf16x8 af[4], bf[4];
        #pragma unroll
        for (int i = 0; i < 4; ++i) {
            af[i] = *(const bf16x8*)(As + (wm * 64 + i * 16 + (lane & 15)) * 32 + (lane >> 4) * 8);
            bf[i] = *(const bf16x8*)(Bs + (wn * 64 + i * 16 + (lane & 15)) * 32 + (lane >> 4) * 8);
        }
        #pragma unroll
        for (int mi = 0; mi < 4; ++mi)
            #pragma unroll
            for (int ni = 0; ni < 4; ++ni)
                acc[mi][ni] = __builtin_amdgcn_mfma_f32_16x16x32_bf16(af[mi], bf[ni], acc[mi][ni], 0, 0, 0);
    }
    #pragma unroll
    for (int mi = 0; mi < 4; ++mi) {
        int rb = mt * 128 + wm * 64 + mi * 16 + ((lane >> 4) << 2);
        #pragma unroll
        for (int ni = 0; ni < 4; ++ni) {
            int col = n0 + wn * 64 + ni * 16 + (lane & 15);
            float bv = b2p[e * DD + col];
            #pragma unroll
            for (int r = 0; r < 4; ++r) {
                int row = rb + r;
                if (row < cnt)
                    slot_out[(size_t)(bs + row) * DD + col] = acc[mi][ni][r] + bv;
            }
        }
    }
}

__global__ __launch_bounds__(192) void k_combine(const float* __restrict__ xr,
                                                 const float* __restrict__ slot_out,
                                                 const int* __restrict__ gate_e,
                                                 const float* __restrict__ gate_v,
                                                 const int* __restrict__ gate_pos,
                                                 const int* __restrict__ base,
                                                 float* __restrict__ out) {
    int t = blockIdx.x;
    int e0 = gate_e[2 * t], e1 = gate_e[2 * t + 1];
    float g0 = gate_v[2 * t], g1 = gate_v[2 * t + 1];
    int s0 = base[e0] + gate_pos[2 * t];
    int s1 = base[e1] + gate_pos[2 * t + 1];
    int c = threadIdx.x * 4;
    float4 xv = *reinterpret_cast<const float4*>(xr + (size_t)t * DD + c);
    float4 a  = *reinterpret_cast<const float4*>(slot_out + (size_t)s0 * DD + c);
    float4 bq = *reinterpret_cast<const float4*>(slot_out + (size_t)s1 * DD + c);
    float4 r;
    r.x = xv.x + g0 * a.x + g1 * bq.x;
    r.y = xv.y + g0 * a.y + g1 * bq.y;
    r.z = xv.z + g0 * a.z + g1 * bq.z;
    r.w = xv.w + g0 * a.w + g1 * bq.w;
    *reinterpret_cast<float4*>(out + (size_t)t * DD + c) = r;
}

// ---------------- launch ----------------

extern "C" void kernel_launch(void* const* d_in, const int* in_sizes, int n_in,
                              void* d_out, int out_size, void* d_ws, size_t ws_size,
                              hipStream_t stream) {
    const float* x      = (const float*)d_in[0];
    const float* ln1_w  = (const float*)d_in[1];
    const float* ln1_b  = (const float*)d_in[2];
    const float* ln2_w  = (const float*)d_in[3];
    const float* ln2_b  = (const float*)d_in[4];
    const float* w_qkv  = (const float*)d_in[5];
    const float* b_qkv  = (const float*)d_in[6];
    const float* w_out  = (const float*)d_in[7];
    const float* b_out  = (const float*)d_in[8];
    const float* gate_w = (const float*)d_in[9];
    const float* w1     = (const float*)d_in[10];
    const float* b1     = (const float*)d_in[11];
    const float* w2     = (const float*)d_in[12];
    const float* b2     = (const float*)d_in[13];
    float* out = (float*)d_out;

    char* p = (char*)d_ws;
    auto alloc = [&](size_t bytes) -> void* {
        void* r = (void*)p;
        p += (bytes + 255) & ~(size_t)255;
        return r;
    };
    u16*   ln1H     = (u16*)alloc((size_t)NTOK * DD * 2);
    u16*   ln1L     = (u16*)alloc((size_t)NTOK * DD * 2);
    float* qkvb     = (float*)alloc((size_t)NTOK * D3 * 4);
    u16*   qHb      = (u16*)alloc((size_t)NBH * SS * HDIM * 2);
    u16*   qLb      = (u16*)alloc((size_t)NBH * SS * HDIM * 2);
    u16*   kHb      = (u16*)alloc((size_t)NBH * SS * HDIM * 2);
    u16*   kLb      = (u16*)alloc((size_t)NBH * SS * HDIM * 2);
    u16*   vtHb     = (u16*)alloc((size_t)NBH * SS * HDIM * 2);
    u16*   vtLb     = (u16*)alloc((size_t)NBH * SS * HDIM * 2);
    u16*   attn_oH  = (u16*)alloc((size_t)NTOK * DD * 2);
    u16*   attn_oL  = (u16*)alloc((size_t)NTOK * DD * 2);
    float* x_resid  = (float*)alloc((size_t)NTOK * DD * 4);
    float* moe_in   = (float*)alloc((size_t)NTOK * DD * 4);
    u16*   Xbf      = (u16*)alloc((size_t)NTOK * DD * 2);
    u16*   hbuf     = (u16*)alloc((size_t)NSLOT * FF * 2);
    float* slot_out = (float*)alloc((size_t)NSLOT * DD * 4);
    u16*   wqkvtH   = (u16*)alloc((size_t)D3 * DD * 2);
    u16*   wqkvtL   = (u16*)alloc((size_t)D3 * DD * 2);
    u16*   wouttH   = (u16*)alloc((size_t)DD * DD * 2);
    u16*   wouttL   = (u16*)alloc((size_t)DD * DD * 2);
    // region: [S fp32 25.2MB][PH 12.6MB][PL 12.6MB]; then w1t/w2t (37.75MB) reuse
    // [0:37.75) AFTER attention is done (PH tail overlaps w1t, PL is disjoint).
    const size_t S_BYTES  = (size_t)NBH * SS * SS * 4;   // 25165824
    const size_t PH_BYTES = (size_t)NBH * SS * SS * 2;   // 12582912
    char* region = (char*)alloc(S_BYTES + 2 * PH_BYTES); // 50.33 MB
    float* Smat = (float*)region;
    u16*   PHb  = (u16*)(region + S_BYTES);
    u16*   PLb  = (u16*)(region + S_BYTES + PH_BYTES);
    u16*   w1t  = (u16*)region;
    u16*   w2t  = (u16*)region;
    int*   gate_e   = (int*)alloc(NSLOT * 4);
    float* gate_v   = (float*)alloc(NSLOT * 4);
    int*   gate_pos = (int*)alloc(NSLOT * 4);
    int*   counts   = (int*)alloc(EE * 4);
    int*   base     = (int*)alloc(EE * 4);
    int*   slot_tok = (int*)alloc(NSLOT * 4);

    k_zero<<<1, 32, 0, stream>>>(counts);
    k_ln_split<<<NTOK, 256, 0, stream>>>(x, ln1_w, ln1_b, ln1H, ln1L);
    k_cvtT_split<<<dim3(D3 / 32, DD / 32), 256, 0, stream>>>(w_qkv, wqkvtH, wqkvtL, DD, D3);
    // QKV: split-bf16 x3 MFMA GEMM, fp32 out
    k_gemm_x3b<0><<<dim3(D3 / 128, NTOK / 128, 1), 256, 0, stream>>>(
        ln1H, ln1L, DD, 0, wqkvtH, wqkvtL, DD, 0, b_qkv, nullptr, qkvb, D3, 0, DD, 1.f);
    // attention: cvt -> QK^T (batched x3) -> softmax(split) -> PV (x3)
    k_attn_cvt<<<dim3(SS / 64, NBH), 256, 0, stream>>>(qkvb, qHb, qLb, kHb, kLb, vtHb, vtLb);
    k_gemm_x3b<0><<<dim3(SS / 128, SS / 128, NBH), 256, 0, stream>>>(
        qHb, qLb, HDIM, (size_t)SS * HDIM, kHb, kLb, HDIM, (size_t)SS * HDIM,
        nullptr, nullptr, Smat, SS, (size_t)SS * SS, HDIM, 0.125f);
    k_sm_split<<<NBH * SS, 64, 0, stream>>>(Smat, PHb, PLb);
    k_pv_x3<<<dim3(SS / 128, NBH), 256, 0, stream>>>(PHb, PLb, vtHb, vtLb, attn_oH, attn_oL);
    k_cvtT_split<<<dim3(DD / 32, DD / 32), 256, 0, stream>>>(w_out, wouttH, wouttL, DD, DD);
    // out-proj: split-bf16 x3 MFMA GEMM + residual
    k_gemm_x3b<1><<<dim3(DD / 128, NTOK / 128, 1), 256, 0, stream>>>(
        attn_oH, attn_oL, DD, 0, wouttH, wouttL, DD, 0, b_out, x, x_resid, DD, 0, DD, 1.f);
    k_ln_dual<<<NTOK, 256, 0, stream>>>(x_resid, ln2_w, ln2_b, moe_in, Xbf);
    k_gate<<<NTOK, 64, 0, stream>>>(moe_in, gate_w, gate_e, gate_v, gate_pos, counts);
    k_scan<<<1, 1, 0, stream>>>(counts, base);
    k_fill<<<(NSLOT + 255) / 256, 256, 0, stream>>>(gate_e, gate_pos, base, slot_tok);
    // w1 [E][D][F] -> w1t [E][F][D] bf16 (region reuse; attention buffers dead)
    k_cvtT<<<dim3(FF / 32, DD / 32, EE), 256, 0, stream>>>(w1, w1t, DD, FF);
    k_moe1_mm<<<dim3(FF / 128, NTOK / 128, EE), 256, 0, stream>>>(
        Xbf, w1t, b1, slot_tok, base, counts, hbuf);
    k_cvtT<<<dim3(DD / 32, FF / 32, EE), 256, 0, stream>>>(w2, w2t, FF, DD);
    k_moe2_mm<<<dim3(DD / 128, NTOK / 128, EE), 256, 0, stream>>>(
        hbuf, w2t, b2, base, counts, slot_out);
    k_combine<<<NTOK, 192, 0, stream>>>(x_resid, slot_out, gate_e, gate_v, gate_pos,
                                        base, out);
}